// Round 1
// 506.336 us; speedup vs baseline: 1.0515x; 1.0515x over previous
//
#include <hip/hip_runtime.h>
#include <hip/hip_bf16.h>

#define NB 8192   // batch
#define ND 1024   // feature dim

typedef __attribute__((ext_vector_type(8))) short bf16x8;
typedef __attribute__((ext_vector_type(4))) float f32x4;

__device__ __forceinline__ void async16(const void* g, void* l) {
  __builtin_amdgcn_global_load_lds(
      (const __attribute__((address_space(1))) void*)g,
      (__attribute__((address_space(3))) void*)l,
      16, 0, 0);
}

__device__ __forceinline__ unsigned short f2bf(float f) {
  union { float f; unsigned u; } a; a.f = f;
  unsigned u = a.u;
  return (unsigned short)((u + 0x7fffu + ((u >> 16) & 1u)) >> 16);  // RNE
}

// ---------------------------------------------------------------------------
// Mask prep: detect bool-byte vs int32 layout, emit float mask.
__global__ void prep_mask(const unsigned char* __restrict__ raw,
                          float* __restrict__ nmask) {
  __shared__ int flag;
  if (threadIdx.x == 0) flag = 0;
  __syncthreads();
  int any = 0;
  for (int i = threadIdx.x; i < NB; i += 256)
    if ((i & 3) != 0 && raw[i] != 0) any = 1;
  if (any) atomicOr(&flag, 1);
  __syncthreads();
  if (flag) {  // 1-byte bool layout
    for (int i = threadIdx.x; i < NB; i += 256)
      nmask[i] = raw[i] ? 1.0f : 0.0f;
  } else {     // int32 layout
    const int* ri = (const int*)raw;
    for (int i = threadIdx.x; i < NB; i += 256)
      nmask[i] = ri[i] ? 1.0f : 0.0f;
  }
}

// ---------------------------------------------------------------------------
// L2-normalize rows of visual/textual feats (f32 in) -> bf16 out.
__global__ void norm_cast(const float* __restrict__ vis,
                          const float* __restrict__ txt,
                          unsigned short* __restrict__ vb,
                          unsigned short* __restrict__ tb) {
  const float* src = blockIdx.y ? txt : vis;
  unsigned short* dst = blockIdx.y ? tb : vb;
  int row = blockIdx.x;
  int t = threadIdx.x;
  float4 x = ((const float4*)(src + (size_t)row * ND))[t];
  float ss = x.x * x.x + x.y * x.y + x.z * x.z + x.w * x.w;
  #pragma unroll
  for (int m = 32; m; m >>= 1) ss += __shfl_xor(ss, m);
  __shared__ float sred[4];
  if ((t & 63) == 0) sred[t >> 6] = ss;
  __syncthreads();
  float tot = sred[0] + sred[1] + sred[2] + sred[3];
  float inv = 1.0f / fmaxf(sqrtf(tot), 1e-12f);
  ushort4 o;
  o.x = f2bf(x.x * inv); o.y = f2bf(x.y * inv);
  o.z = f2bf(x.z * inv); o.w = f2bf(x.w * inv);
  ((ushort4*)dst)[(size_t)row * (ND / 4) + t] = o;
}

// ---------------------------------------------------------------------------
// Fused GEMM + masked-exp row-sum, 256x256 tile / 8-phase counted-vmcnt
// schedule (guide §5 template: T1 XCD swizzle + T3/T4 8-phase counted vmcnt +
// T5 setprio; T2-equivalent XOR chunk swizzle kept from previous version,
// measured SQ_LDS_BANK_CONFLICT == 0).
//
// Geometry: BM=BN=256, BK=64. 512 threads = 8 waves (2M x 4N); per-wave
// output 128x64 = acc[8][4] f32x4. LDS: 2 bufs x (A 32KB + B 32KB) = 128KB.
// K-tile even -> buf0, odd -> buf1; iteration = 2 K-tiles, 8 phases.
//
// Swizzle: stage lane l fetches global chunk (l&7)^(l>>3), LDS linear
// (global_load_lds contract: wave-uniform base + lane*16). LDS row r pos p
// holds global chunk p^(r&7); reads use pos = (kk*4+quad)^(r&7).
//
// Per-iteration schedule (tt -> K-tiles k0=2tt [buf0], k1=2tt+1 [buf1]):
//  P1: rd b,a(mh0) of buf0 | stage K(k1)   Bh0 | bar lgkm0 prio MFMA(r0-3,n0-1) bar
//  P2: rd a2(mh1)  of buf0 | stage K(k1)   Bh1 | bar lgkm0 prio MFMA(r0-3,n2-3) bar
//  P3:                     | stage K(k0+2) Ah0 | bar       prio MFMA(r4-7,n0-1) bar
//  P4:                     | stage K(k0+2) Ah1 | vmcnt(4)  bar prio MFMA(r4-7,n2-3) bar
//  P5: rd b,a(mh0) of buf1 | stage K(k0+2) Bh0 | bar lgkm0 prio MFMA bar
//  P6: rd a2(mh1)  of buf1 | stage K(k0+2) Bh1 | bar lgkm0 prio MFMA bar
//  P7:                     | stage K(k1+2) Ah0 | bar       prio MFMA bar
//  P8:                     | stage K(k1+2) Ah1 | vmcnt(4)  bar prio MFMA bar
// Buffer reads finish by P2/P6 -> staging into the same buffer 1 phase later
// is race-free (closing barriers order it). vmcnt(4) = 2 half-tiles in
// flight, 2-phase issue->wait slack; tail iteration uses vmcnt(0) at P4.
#define AS_BARRIER asm volatile("s_barrier" ::: "memory")
#define LGKM0 asm volatile("s_waitcnt lgkmcnt(0)" ::: "memory")
#define VMCNT(n) asm volatile("s_waitcnt vmcnt(" #n ")" ::: "memory")

#define STG(GB, LB, KT, H) do {                                               \
    async16(GB + (size_t)((H) * 128 + 0) * ND + (KT) * 64,                    \
            LB + ((H) * 128 + 0) * 128);                                      \
    async16(GB + (size_t)((H) * 128 + 64) * ND + (KT) * 64,                   \
            LB + ((H) * 128 + 64) * 128);                                     \
  } while (0)

#define RDA(BUF, MH, DST) do {                                                \
    _Pragma("unroll") for (int mi_ = 0; mi_ < 4; ++mi_) {                     \
      DST[mi_][0] = *(const bf16x8*)&As[BUF][(rA + (MH)*64 + mi_*16)*64 + c0*8]; \
      DST[mi_][1] = *(const bf16x8*)&As[BUF][(rA + (MH)*64 + mi_*16)*64 + c1*8]; \
    } } while (0)

#define RDB(BUF) do {                                                         \
    _Pragma("unroll") for (int ni_ = 0; ni_ < 4; ++ni_) {                     \
      b[ni_][0] = *(const bf16x8*)&Bs[BUF][(rB + ni_*16)*64 + c0*8];          \
      b[ni_][1] = *(const bf16x8*)&Bs[BUF][(rB + ni_*16)*64 + c1*8];          \
    } } while (0)

#define MFMAQ(AF, RB, NH) do {                                                \
    _Pragma("unroll") for (int mi_ = 0; mi_ < 4; ++mi_)                       \
    _Pragma("unroll") for (int ni_ = 0; ni_ < 2; ++ni_)                       \
    _Pragma("unroll") for (int kk_ = 0; kk_ < 2; ++kk_)                       \
      acc[(RB) + mi_][(NH)*2 + ni_] =                                         \
          __builtin_amdgcn_mfma_f32_16x16x32_bf16(                            \
              AF[mi_][kk_], b[(NH)*2 + ni_][kk_],                             \
              acc[(RB) + mi_][(NH)*2 + ni_], 0, 0, 0);                        \
  } while (0)

__global__ __launch_bounds__(512, 2) void gemm_fused(
    const unsigned short* __restrict__ vb, const unsigned short* __restrict__ tb,
    const float* __restrict__ nmask, float* __restrict__ partial) {
  __shared__ unsigned short As[2][256 * 64];   // 64 KB
  __shared__ unsigned short Bs[2][256 * 64];   // 64 KB
  __shared__ float part[256][4];               // 4 KB

  // XCD-aware bijective swizzle: nwg = 1024, 1024 % 8 == 0.
  int lin = blockIdx.y * 32 + blockIdx.x;
  lin = (lin & 7) * 128 + (lin >> 3);
  const int bx = lin & 31, by = lin >> 5;
  const int i0 = by * 256, j0 = bx * 256;

  const int t = threadIdx.x;
  const int w = t >> 6, l = t & 63;
  const int quad = l >> 4, l15 = l & 15;
  const int wm = w >> 2, wn = w & 3;           // 2M x 4N waves

  // Staging lane geometry (pre-swizzled global source, linear LDS dest).
  const int lrow = l >> 3;
  const int lch = (l & 7) ^ lrow;
  const unsigned short* Ag = vb + (size_t)(i0 + w * 8 + lrow) * ND + lch * 8;
  const unsigned short* Bg = tb + (size_t)(j0 + w * 8 + lrow) * ND + lch * 8;
  char* AL0 = (char*)&As[0][0] + w * 1024;
  char* AL1 = (char*)&As[1][0] + w * 1024;
  char* BL0 = (char*)&Bs[0][0] + w * 1024;
  char* BL1 = (char*)&Bs[1][0] + w * 1024;

  // ds_read lane geometry
  const int rA = wm * 128 + l15;               // + mh*64 + mi*16
  const int rB = wn * 64 + l15;                // + ni*16
  const int c0 = quad ^ (l & 7);               // kk=0 chunk position
  const int c1 = (4 + quad) ^ (l & 7);         // kk=1 chunk position

  // Prologue: K0 fully -> buf0 (8 loads), K1 A-halves -> buf1 (4 loads).
  STG(Ag, AL0, 0, 0); STG(Ag, AL0, 0, 1);
  STG(Bg, BL0, 0, 0); STG(Bg, BL0, 0, 1);
  STG(Ag, AL1, 1, 0); STG(Ag, AL1, 1, 1);
  VMCNT(4);           // K0 landed; K1-A (4 loads) still in flight
  AS_BARRIER;

  bf16x8 a[4][2], a2[4][2], b[4][2];
  f32x4 acc[8][4] = {};

  #pragma unroll 1
  for (int tt = 0; tt < 8; ++tt) {
    const int k0 = 2 * tt, k1 = 2 * tt + 1;
    const bool pf = (tt < 7);
    // ---- P1
    RDB(0); RDA(0, 0, a);
    STG(Bg, BL1, k1, 0);
    AS_BARRIER; LGKM0;
    __builtin_amdgcn_s_setprio(1); MFMAQ(a, 0, 0); __builtin_amdgcn_s_setprio(0);
    AS_BARRIER;
    // ---- P2
    RDA(0, 1, a2);
    STG(Bg, BL1, k1, 1);
    AS_BARRIER; LGKM0;
    __builtin_amdgcn_s_setprio(1); MFMAQ(a, 0, 1); __builtin_amdgcn_s_setprio(0);
    AS_BARRIER;
    // ---- P3 (buf0 fully consumed into regs -> safe to restage)
    if (pf) STG(Ag, AL0, k0 + 2, 0);
    AS_BARRIER;
    __builtin_amdgcn_s_setprio(1); MFMAQ(a2, 4, 0); __builtin_amdgcn_s_setprio(0);
    AS_BARRIER;
    // ---- P4 (counted wait: K(k1) fully landed, K(k0+2)-A may be in flight)
    if (pf) { STG(Ag, AL0, k0 + 2, 1); VMCNT(4); } else { VMCNT(0); }
    AS_BARRIER;
    __builtin_amdgcn_s_setprio(1); MFMAQ(a2, 4, 1); __builtin_amdgcn_s_setprio(0);
    AS_BARRIER;
    // ---- P5
    RDB(1); RDA(1, 0, a);
    if (pf) STG(Bg, BL0, k0 + 2, 0);
    AS_BARRIER; LGKM0;
    __builtin_amdgcn_s_setprio(1); MFMAQ(a, 0, 0); __builtin_amdgcn_s_setprio(0);
    AS_BARRIER;
    // ---- P6
    RDA(1, 1, a2);
    if (pf) STG(Bg, BL0, k0 + 2, 1);
    AS_BARRIER; LGKM0;
    __builtin_amdgcn_s_setprio(1); MFMAQ(a, 0, 1); __builtin_amdgcn_s_setprio(0);
    AS_BARRIER;
    // ---- P7
    if (pf) STG(Ag, AL1, k1 + 2, 0);
    AS_BARRIER;
    __builtin_amdgcn_s_setprio(1); MFMAQ(a2, 4, 0); __builtin_amdgcn_s_setprio(0);
    AS_BARRIER;
    // ---- P8
    if (pf) { STG(Ag, AL1, k1 + 2, 1); VMCNT(4); }
    AS_BARRIER;
    __builtin_amdgcn_s_setprio(1); MFMAQ(a2, 4, 1); __builtin_amdgcn_s_setprio(0);
    AS_BARRIER;
  }

  // Epilogue: val = exp(sim/T)*max(n_row,n_col); row-sum over this block's
  // 256 cols. C/D layout (m89): col = l&15 (from B), row = quad*4 + reg.
  const float SCALE = 20.60992915555662f;  // log2(e)/0.07
  float ncol[4];
  #pragma unroll
  for (int ni = 0; ni < 4; ++ni) ncol[ni] = nmask[j0 + wn * 64 + ni * 16 + l15];

  #pragma unroll
  for (int mi = 0; mi < 8; ++mi) {
    float nrow[4], ra[4] = {0.f, 0.f, 0.f, 0.f};
    #pragma unroll
    for (int r = 0; r < 4; ++r)
      nrow[r] = nmask[i0 + wm * 128 + mi * 16 + quad * 4 + r];
    #pragma unroll
    for (int ni = 0; ni < 4; ++ni)
      #pragma unroll
      for (int r = 0; r < 4; ++r)
        ra[r] += exp2f(acc[mi][ni][r] * SCALE) * fmaxf(nrow[r], ncol[ni]);
    #pragma unroll
    for (int r = 0; r < 4; ++r) {
      float v = ra[r];
      v += __shfl_xor(v, 1); v += __shfl_xor(v, 2);
      v += __shfl_xor(v, 4); v += __shfl_xor(v, 8);
      if (l15 == 0) part[wm * 128 + mi * 16 + quad * 4 + r][wn] = v;
    }
  }
  __syncthreads();
  if (t < 256)
    partial[(size_t)bx * NB + i0 + t] =
        part[t][0] + part[t][1] + part[t][2] + part[t][3];
}

// ---------------------------------------------------------------------------
// loss = mean_i log(sum_c partial[c][i] + 1e-8). 32 blocks x 256 threads.
__global__ void finalize(const float* __restrict__ partial, float* __restrict__ out) {
  int r = blockIdx.x * 256 + threadIdx.x;
  float s = 0.f;
  #pragma unroll 4
  for (int c = 0; c < 32; ++c) s += partial[(size_t)c * NB + r];
  float lg = logf(s + 1e-8f);
  #pragma unroll
  for (int m = 32; m; m >>= 1) lg += __shfl_xor(lg, m);
  __shared__ float sred[4];
  if ((threadIdx.x & 63) == 0) sred[threadIdx.x >> 6] = lg;
  __syncthreads();
  if (threadIdx.x == 0)
    atomicAdd(out, (sred[0] + sred[1] + sred[2] + sred[3]) * (1.0f / NB));
}

// ---------------------------------------------------------------------------
extern "C" void kernel_launch(void* const* d_in, const int* in_sizes, int n_in,
                              void* d_out, int out_size, void* d_ws, size_t ws_size,
                              hipStream_t stream) {
  const float* vis = (const float*)d_in[0];
  const float* txt = (const float*)d_in[1];
  // d_in[2] transport_matrix: unused. d_in[3] clean mask: unused.
  const unsigned char* noisy = (const unsigned char*)d_in[4];
  float* out = (float*)d_out;

  char* ws = (char*)d_ws;
  unsigned short* vb = (unsigned short*)ws;                           // 16 MB bf16
  unsigned short* tb = (unsigned short*)(ws + ((size_t)16 << 20));    // 16 MB bf16
  float* nmask = (float*)(ws + ((size_t)32 << 20));                   // 32 KB
  float* partial = (float*)(ws + ((size_t)32 << 20) + (64 << 10));    // 1 MB

  hipMemsetAsync(d_out, 0, sizeof(float), stream);
  prep_mask<<<1, 256, 0, stream>>>(noisy, nmask);
  norm_cast<<<dim3(NB, 2), 256, 0, stream>>>(vis, txt, vb, tb);
  gemm_fused<<<dim3(NB / 256, NB / 256), 512, 0, stream>>>(vb, tb, nmask, partial);
  finalize<<<NB / 256, 256, 0, stream>>>(partial, out);
}

// Round 2
// 497.321 us; speedup vs baseline: 1.0706x; 1.0181x over previous
//
#include <hip/hip_runtime.h>
#include <hip/hip_bf16.h>

#define NB 8192   // batch
#define ND 1024   // feature dim

typedef __attribute__((ext_vector_type(8))) short bf16x8;
typedef __attribute__((ext_vector_type(4))) float f32x4;

__device__ __forceinline__ void async16(const void* g, void* l) {
  __builtin_amdgcn_global_load_lds(
      (const __attribute__((address_space(1))) void*)g,
      (__attribute__((address_space(3))) void*)l,
      16, 0, 0);
}

// Generic->LDS(as3) pointer to 32-bit LDS byte address (for asm ds_read).
__device__ __forceinline__ unsigned ldsaddr(const void* p) {
  return (unsigned)(size_t)(const __attribute__((address_space(3))) void*)p;
}

// Inline-asm ds_read_b128: invisible to SIInsertWaitcnts, so no
// compiler-inserted vmcnt drain against in-flight global_load_lds DMA
// (the round-1 kernel's counted-vmcnt pipeline measured +0% vs a drained
// one -- diagnostic for exactly that conservative alias wait).
template <int IMM>
__device__ __forceinline__ bf16x8 dsr(unsigned a) {
  bf16x8 r;
  asm volatile("ds_read_b128 %0, %1 offset:%2" : "=v"(r) : "v"(a), "i"(IMM));
  return r;
}

__device__ __forceinline__ unsigned short f2bf(float f) {
  union { float f; unsigned u; } a; a.f = f;
  unsigned u = a.u;
  return (unsigned short)((u + 0x7fffu + ((u >> 16) & 1u)) >> 16);  // RNE
}

// ---------------------------------------------------------------------------
// Mask prep: detect bool-byte vs int32 layout, emit float mask.
__global__ void prep_mask(const unsigned char* __restrict__ raw,
                          float* __restrict__ nmask) {
  __shared__ int flag;
  if (threadIdx.x == 0) flag = 0;
  __syncthreads();
  int any = 0;
  for (int i = threadIdx.x; i < NB; i += 256)
    if ((i & 3) != 0 && raw[i] != 0) any = 1;
  if (any) atomicOr(&flag, 1);
  __syncthreads();
  if (flag) {  // 1-byte bool layout
    for (int i = threadIdx.x; i < NB; i += 256)
      nmask[i] = raw[i] ? 1.0f : 0.0f;
  } else {     // int32 layout
    const int* ri = (const int*)raw;
    for (int i = threadIdx.x; i < NB; i += 256)
      nmask[i] = ri[i] ? 1.0f : 0.0f;
  }
}

// ---------------------------------------------------------------------------
// L2-normalize rows of visual/textual feats (f32 in) -> bf16 out.
__global__ void norm_cast(const float* __restrict__ vis,
                          const float* __restrict__ txt,
                          unsigned short* __restrict__ vb,
                          unsigned short* __restrict__ tb) {
  const float* src = blockIdx.y ? txt : vis;
  unsigned short* dst = blockIdx.y ? tb : vb;
  int row = blockIdx.x;
  int t = threadIdx.x;
  float4 x = ((const float4*)(src + (size_t)row * ND))[t];
  float ss = x.x * x.x + x.y * x.y + x.z * x.z + x.w * x.w;
  #pragma unroll
  for (int m = 32; m; m >>= 1) ss += __shfl_xor(ss, m);
  __shared__ float sred[4];
  if ((t & 63) == 0) sred[t >> 6] = ss;
  __syncthreads();
  float tot = sred[0] + sred[1] + sred[2] + sred[3];
  float inv = 1.0f / fmaxf(sqrtf(tot), 1e-12f);
  ushort4 o;
  o.x = f2bf(x.x * inv); o.y = f2bf(x.y * inv);
  o.z = f2bf(x.z * inv); o.w = f2bf(x.w * inv);
  ((ushort4*)dst)[(size_t)row * (ND / 4) + t] = o;
}

// ---------------------------------------------------------------------------
// Fused GEMM + masked-exp row-sum, 256x256 tile / 8-phase counted-vmcnt
// schedule. Round-2 change: LDS reads via inline-asm ds_read_b128 with
// compile-time offset immediates + explicit lgkmcnt(0) + sched_barrier(0)
// (rule #18), so the compiler's conservative LDS-DMA alias waits are gone
// and the counted vmcnt(4) pipeline actually stays in flight.
//
// LDS byte layout (per object): buf*32768 + row*128 + pos*16.
// Read row = (lane-base rA/rB) + MH*64 + mi*16  -> imm = BUF*32768 +
// MH*8192 + mi*2048 (all <= 47104, fits 16-bit offset).
// Chunk swizzle: pos c0 = quad^(l&7); kk=1 chunk c1 = c0^4 -> byte addr ^64.
#define AS_BARRIER asm volatile("s_barrier" ::: "memory")
#define LGKM0 do { asm volatile("s_waitcnt lgkmcnt(0)" ::: "memory"); \
                   __builtin_amdgcn_sched_barrier(0); } while (0)
#define VMCNT(n) asm volatile("s_waitcnt vmcnt(" #n ")" ::: "memory")

#define STG(GB, LB, KT, H) do {                                               \
    async16(GB + (size_t)((H) * 128 + 0) * ND + (KT) * 64,                    \
            LB + ((H) * 128 + 0) * 128);                                      \
    async16(GB + (size_t)((H) * 128 + 64) * ND + (KT) * 64,                   \
            LB + ((H) * 128 + 64) * 128);                                     \
  } while (0)

#define RDA(BUF, MH, DST) do {                                                \
    DST[0][0] = dsr<(BUF)*32768 + (MH)*8192 + 0   >(aA0);                     \
    DST[0][1] = dsr<(BUF)*32768 + (MH)*8192 + 0   >(aA1);                     \
    DST[1][0] = dsr<(BUF)*32768 + (MH)*8192 + 2048>(aA0);                     \
    DST[1][1] = dsr<(BUF)*32768 + (MH)*8192 + 2048>(aA1);                     \
    DST[2][0] = dsr<(BUF)*32768 + (MH)*8192 + 4096>(aA0);                     \
    DST[2][1] = dsr<(BUF)*32768 + (MH)*8192 + 4096>(aA1);                     \
    DST[3][0] = dsr<(BUF)*32768 + (MH)*8192 + 6144>(aA0);                     \
    DST[3][1] = dsr<(BUF)*32768 + (MH)*8192 + 6144>(aA1);                     \
  } while (0)

#define RDB(BUF) do {                                                         \
    b[0][0] = dsr<(BUF)*32768 + 0   >(aB0);                                   \
    b[0][1] = dsr<(BUF)*32768 + 0   >(aB1);                                   \
    b[1][0] = dsr<(BUF)*32768 + 2048>(aB0);                                   \
    b[1][1] = dsr<(BUF)*32768 + 2048>(aB1);                                   \
    b[2][0] = dsr<(BUF)*32768 + 4096>(aB0);                                   \
    b[2][1] = dsr<(BUF)*32768 + 4096>(aB1);                                   \
    b[3][0] = dsr<(BUF)*32768 + 6144>(aB0);                                   \
    b[3][1] = dsr<(BUF)*32768 + 6144>(aB1);                                   \
  } while (0)

#define MFMAQ(AF, RB, NH) do {                                                \
    _Pragma("unroll") for (int mi_ = 0; mi_ < 4; ++mi_)                       \
    _Pragma("unroll") for (int ni_ = 0; ni_ < 2; ++ni_)                       \
    _Pragma("unroll") for (int kk_ = 0; kk_ < 2; ++kk_)                       \
      acc[(RB) + mi_][(NH)*2 + ni_] =                                         \
          __builtin_amdgcn_mfma_f32_16x16x32_bf16(                            \
              AF[mi_][kk_], b[(NH)*2 + ni_][kk_],                             \
              acc[(RB) + mi_][(NH)*2 + ni_], 0, 0, 0);                        \
  } while (0)

__global__ __launch_bounds__(512, 2) void gemm_fused(
    const unsigned short* __restrict__ vb, const unsigned short* __restrict__ tb,
    const float* __restrict__ nmask, float* __restrict__ partial) {
  __shared__ unsigned short As[2][256 * 64];   // 64 KB
  __shared__ unsigned short Bs[2][256 * 64];   // 64 KB
  __shared__ float part[256][4];               // 4 KB

  // XCD-aware bijective swizzle: nwg = 1024, 1024 % 8 == 0.
  int lin = blockIdx.y * 32 + blockIdx.x;
  lin = (lin & 7) * 128 + (lin >> 3);
  const int bx = lin & 31, by = lin >> 5;
  const int i0 = by * 256, j0 = bx * 256;

  const int t = threadIdx.x;
  const int w = t >> 6, l = t & 63;
  const int quad = l >> 4, l15 = l & 15;
  const int wm = w >> 2, wn = w & 3;           // 2M x 4N waves

  // Staging lane geometry (pre-swizzled global source, linear LDS dest).
  const int lrow = l >> 3;
  const int lch = (l & 7) ^ lrow;
  const unsigned short* Ag = vb + (size_t)(i0 + w * 8 + lrow) * ND + lch * 8;
  const unsigned short* Bg = tb + (size_t)(j0 + w * 8 + lrow) * ND + lch * 8;
  char* AL0 = (char*)&As[0][0] + w * 1024;
  char* AL1 = (char*)&As[1][0] + w * 1024;
  char* BL0 = (char*)&Bs[0][0] + w * 1024;
  char* BL1 = (char*)&Bs[1][0] + w * 1024;

  // ds_read lane geometry: per-lane byte addresses; subtile walk via
  // offset: immediates; kk=1 chunk via addr^64 (c1 = c0^4).
  const int rA = wm * 128 + l15;               // + MH*64 + mi*16 via imm
  const int rB = wn * 64 + l15;                // + ni*16 via imm
  const int c0 = quad ^ (l & 7);
  const unsigned aA0 = ldsaddr(&As[0][0]) + rA * 128 + c0 * 16;
  const unsigned aA1 = aA0 ^ 64;
  const unsigned aB0 = ldsaddr(&Bs[0][0]) + rB * 128 + c0 * 16;
  const unsigned aB1 = aB0 ^ 64;

  // Prologue: K0 fully -> buf0 (8 loads), K1 A-halves -> buf1 (4 loads).
  STG(Ag, AL0, 0, 0); STG(Ag, AL0, 0, 1);
  STG(Bg, BL0, 0, 0); STG(Bg, BL0, 0, 1);
  STG(Ag, AL1, 1, 0); STG(Ag, AL1, 1, 1);
  VMCNT(4);           // K0 landed; K1-A (4 loads) still in flight
  AS_BARRIER;

  bf16x8 a[4][2], a2[4][2], b[4][2];
  f32x4 acc[8][4] = {};

  #pragma unroll 1
  for (int tt = 0; tt < 8; ++tt) {
    const int k0 = 2 * tt, k1 = 2 * tt + 1;
    const bool pf = (tt < 7);
    // ---- P1
    RDB(0); RDA(0, 0, a);
    STG(Bg, BL1, k1, 0);
    AS_BARRIER; LGKM0;
    __builtin_amdgcn_s_setprio(1); MFMAQ(a, 0, 0); __builtin_amdgcn_s_setprio(0);
    AS_BARRIER;
    // ---- P2
    RDA(0, 1, a2);
    STG(Bg, BL1, k1, 1);
    AS_BARRIER; LGKM0;
    __builtin_amdgcn_s_setprio(1); MFMAQ(a, 0, 1); __builtin_amdgcn_s_setprio(0);
    AS_BARRIER;
    // ---- P3 (buf0 fully consumed into regs -> safe to restage)
    if (pf) STG(Ag, AL0, k0 + 2, 0);
    AS_BARRIER;
    __builtin_amdgcn_s_setprio(1); MFMAQ(a2, 4, 0); __builtin_amdgcn_s_setprio(0);
    AS_BARRIER;
    // ---- P4 (counted wait: K(k1) fully landed, K(k0+2)-A may be in flight)
    if (pf) { STG(Ag, AL0, k0 + 2, 1); VMCNT(4); } else { VMCNT(0); }
    AS_BARRIER;
    __builtin_amdgcn_s_setprio(1); MFMAQ(a2, 4, 1); __builtin_amdgcn_s_setprio(0);
    AS_BARRIER;
    // ---- P5
    RDB(1); RDA(1, 0, a);
    if (pf) STG(Bg, BL0, k0 + 2, 0);
    AS_BARRIER; LGKM0;
    __builtin_amdgcn_s_setprio(1); MFMAQ(a, 0, 0); __builtin_amdgcn_s_setprio(0);
    AS_BARRIER;
    // ---- P6
    RDA(1, 1, a2);
    if (pf) STG(Bg, BL0, k0 + 2, 1);
    AS_BARRIER; LGKM0;
    __builtin_amdgcn_s_setprio(1); MFMAQ(a, 0, 1); __builtin_amdgcn_s_setprio(0);
    AS_BARRIER;
    // ---- P7
    if (pf) STG(Ag, AL1, k1 + 2, 0);
    AS_BARRIER;
    __builtin_amdgcn_s_setprio(1); MFMAQ(a2, 4, 0); __builtin_amdgcn_s_setprio(0);
    AS_BARRIER;
    // ---- P8
    if (pf) { STG(Ag, AL1, k1 + 2, 1); VMCNT(4); }
    AS_BARRIER;
    __builtin_amdgcn_s_setprio(1); MFMAQ(a2, 4, 1); __builtin_amdgcn_s_setprio(0);
    AS_BARRIER;
  }

  // Epilogue: val = exp(sim/T)*max(n_row,n_col); row-sum over this block's
  // 256 cols. C/D layout (m89): col = l&15 (from B), row = quad*4 + reg.
  const float SCALE = 20.60992915555662f;  // log2(e)/0.07
  float ncol[4];
  #pragma unroll
  for (int ni = 0; ni < 4; ++ni) ncol[ni] = nmask[j0 + wn * 64 + ni * 16 + l15];

  #pragma unroll
  for (int mi = 0; mi < 8; ++mi) {
    float nrow[4], ra[4] = {0.f, 0.f, 0.f, 0.f};
    #pragma unroll
    for (int r = 0; r < 4; ++r)
      nrow[r] = nmask[i0 + wm * 128 + mi * 16 + quad * 4 + r];
    #pragma unroll
    for (int ni = 0; ni < 4; ++ni)
      #pragma unroll
      for (int r = 0; r < 4; ++r)
        ra[r] += exp2f(acc[mi][ni][r] * SCALE) * fmaxf(nrow[r], ncol[ni]);
    #pragma unroll
    for (int r = 0; r < 4; ++r) {
      float v = ra[r];
      v += __shfl_xor(v, 1); v += __shfl_xor(v, 2);
      v += __shfl_xor(v, 4); v += __shfl_xor(v, 8);
      if (l15 == 0) part[wm * 128 + mi * 16 + quad * 4 + r][wn] = v;
    }
  }
  __syncthreads();
  if (t < 256)
    partial[(size_t)bx * NB + i0 + t] =
        part[t][0] + part[t][1] + part[t][2] + part[t][3];
}

// ---------------------------------------------------------------------------
// loss = mean_i log(sum_c partial[c][i] + 1e-8). 32 blocks x 256 threads.
__global__ void finalize(const float* __restrict__ partial, float* __restrict__ out) {
  int r = blockIdx.x * 256 + threadIdx.x;
  float s = 0.f;
  #pragma unroll 4
  for (int c = 0; c < 32; ++c) s += partial[(size_t)c * NB + r];
  float lg = logf(s + 1e-8f);
  #pragma unroll
  for (int m = 32; m; m >>= 1) lg += __shfl_xor(lg, m);
  __shared__ float sred[4];
  if ((threadIdx.x & 63) == 0) sred[threadIdx.x >> 6] = lg;
  __syncthreads();
  if (threadIdx.x == 0)
    atomicAdd(out, (sred[0] + sred[1] + sred[2] + sred[3]) * (1.0f / NB));
}

// ---------------------------------------------------------------------------
extern "C" void kernel_launch(void* const* d_in, const int* in_sizes, int n_in,
                              void* d_out, int out_size, void* d_ws, size_t ws_size,
                              hipStream_t stream) {
  const float* vis = (const float*)d_in[0];
  const float* txt = (const float*)d_in[1];
  // d_in[2] transport_matrix: unused. d_in[3] clean mask: unused.
  const unsigned char* noisy = (const unsigned char*)d_in[4];
  float* out = (float*)d_out;

  char* ws = (char*)d_ws;
  unsigned short* vb = (unsigned short*)ws;                           // 16 MB bf16
  unsigned short* tb = (unsigned short*)(ws + ((size_t)16 << 20));    // 16 MB bf16
  float* nmask = (float*)(ws + ((size_t)32 << 20));                   // 32 KB
  float* partial = (float*)(ws + ((size_t)32 << 20) + (64 << 10));    // 1 MB

  hipMemsetAsync(d_out, 0, sizeof(float), stream);
  prep_mask<<<1, 256, 0, stream>>>(noisy, nmask);
  norm_cast<<<dim3(NB, 2), 256, 0, stream>>>(vis, txt, vb, tb);
  gemm_fused<<<dim3(NB / 256, NB / 256), 512, 0, stream>>>(vb, tb, nmask, partial);
  finalize<<<NB / 256, 256, 0, stream>>>(partial, out);
}

// Round 4
// 486.038 us; speedup vs baseline: 1.0954x; 1.0232x over previous
//
#include <hip/hip_runtime.h>
#include <hip/hip_bf16.h>

#define NB 8192   // batch
#define ND 1024   // feature dim

typedef __attribute__((ext_vector_type(8))) short bf16x8;
typedef __attribute__((ext_vector_type(4))) float f32x4;

__device__ __forceinline__ void async16(const void* g, void* l) {
  __builtin_amdgcn_global_load_lds(
      (const __attribute__((address_space(1))) void*)g,
      (__attribute__((address_space(3))) void*)l,
      16, 0, 0);
}

// Generic->LDS(as3) pointer to 32-bit LDS byte address (for asm ds_read).
__device__ __forceinline__ unsigned ldsaddr(const void* p) {
  return (unsigned)(size_t)(const __attribute__((address_space(3))) void*)p;
}

// Inline-asm ds_read_b128: invisible to SIInsertWaitcnts -> no compiler
// vmcnt drain against in-flight global_load_lds DMA (round-2: 189 -> <159us).
template <int IMM>
__device__ __forceinline__ bf16x8 dsr(unsigned a) {
  bf16x8 r;
  asm volatile("ds_read_b128 %0, %1 offset:%2" : "=v"(r) : "v"(a), "i"(IMM));
  return r;
}

__device__ __forceinline__ unsigned short f2bf(float f) {
  union { float f; unsigned u; } a; a.f = f;
  unsigned u = a.u;
  return (unsigned short)((u + 0x7fffu + ((u >> 16) & 1u)) >> 16);  // RNE
}

// ---------------------------------------------------------------------------
// Mask prep: detect bool-byte vs int32 layout, emit float mask.
__global__ void prep_mask(const unsigned char* __restrict__ raw,
                          float* __restrict__ nmask) {
  __shared__ int flag;
  if (threadIdx.x == 0) flag = 0;
  __syncthreads();
  int any = 0;
  for (int i = threadIdx.x; i < NB; i += 256)
    if ((i & 3) != 0 && raw[i] != 0) any = 1;
  if (any) atomicOr(&flag, 1);
  __syncthreads();
  if (flag) {  // 1-byte bool layout
    for (int i = threadIdx.x; i < NB; i += 256)
      nmask[i] = raw[i] ? 1.0f : 0.0f;
  } else {     // int32 layout
    const int* ri = (const int*)raw;
    for (int i = threadIdx.x; i < NB; i += 256)
      nmask[i] = ri[i] ? 1.0f : 0.0f;
  }
}

// ---------------------------------------------------------------------------
// L2-normalize rows of visual/textual feats (f32 in) -> bf16 out.
__global__ void norm_cast(const float* __restrict__ vis,
                          const float* __restrict__ txt,
                          unsigned short* __restrict__ vb,
                          unsigned short* __restrict__ tb) {
  const float* src = blockIdx.y ? txt : vis;
  unsigned short* dst = blockIdx.y ? tb : vb;
  int row = blockIdx.x;
  int t = threadIdx.x;
  float4 x = ((const float4*)(src + (size_t)row * ND))[t];
  float ss = x.x * x.x + x.y * x.y + x.z * x.z + x.w * x.w;
  #pragma unroll
  for (int m = 32; m; m >>= 1) ss += __shfl_xor(ss, m);
  __shared__ float sred[4];
  if ((t & 63) == 0) sred[t >> 6] = ss;
  __syncthreads();
  float tot = sred[0] + sred[1] + sred[2] + sred[3];
  float inv = 1.0f / fmaxf(sqrtf(tot), 1e-12f);
  ushort4 o;
  o.x = f2bf(x.x * inv); o.y = f2bf(x.y * inv);
  o.z = f2bf(x.z * inv); o.w = f2bf(x.w * inv);
  ((ushort4*)dst)[(size_t)row * (ND / 4) + t] = o;
}

// ---------------------------------------------------------------------------
// Fused GEMM + masked-exp row-sum, 256x256 tile / 8-phase counted-vmcnt.
// LDS/MFMA pipe overlap: each phase's ds_reads are ISSUED in the previous
// phase's MFMA window (LDS unit works while matrix pipe runs); the
// lgkmcnt(0) before each consuming MFMA then waits on reads aged >= 1 full
// phase (~free). Read batches per K-tile: R1={a(8),b(8)} needed by P1,
// issued in P4/P8 region right after that buffer's vmcnt(4) guarantee;
// R2={a2(8)} needed by P3, issued in P1/P5 region. WAR discipline in P4/P8
// (live regs: a2, b[2..3]): only dead a+b[0..1] issue pre-MFMA; b[2..3]
// issues post-MFMA behind sched_barrier(0). Safety lgkmcnt(0) at P2/P6
// completes all same-buffer reads (barrier-ordered) before any STG restages
// that buffer.
//
// LDS byte layout: buf*32768 + row*128 + pos*16; chunk swizzle pos =
// (kt*4+quad)^(l&7) -> addr c0 / c0^64. imm = BUF*32768+MH*8192+mi*2048.
#define AS_BARRIER asm volatile("s_barrier" ::: "memory")
#define LGKM0 do { asm volatile("s_waitcnt lgkmcnt(0)" ::: "memory"); \
                   __builtin_amdgcn_sched_barrier(0); } while (0)
#define VMCNT(n) asm volatile("s_waitcnt vmcnt(" #n ")" ::: "memory")
#define SCHED_FENCE __builtin_amdgcn_sched_barrier(0)

#define STG(GB, LB, KT, H) do {                                               \
    async16(GB + (size_t)((H) * 128 + 0) * ND + (KT) * 64,                    \
            LB + ((H) * 128 + 0) * 128);                                      \
    async16(GB + (size_t)((H) * 128 + 64) * ND + (KT) * 64,                   \
            LB + ((H) * 128 + 64) * 128);                                     \
  } while (0)

#define RDA(BUF, MH, DST) do {                                                \
    DST[0][0] = dsr<(BUF)*32768 + (MH)*8192 + 0   >(aA0);                     \
    DST[0][1] = dsr<(BUF)*32768 + (MH)*8192 + 0   >(aA1);                     \
    DST[1][0] = dsr<(BUF)*32768 + (MH)*8192 + 2048>(aA0);                     \
    DST[1][1] = dsr<(BUF)*32768 + (MH)*8192 + 2048>(aA1);                     \
    DST[2][0] = dsr<(BUF)*32768 + (MH)*8192 + 4096>(aA0);                     \
    DST[2][1] = dsr<(BUF)*32768 + (MH)*8192 + 4096>(aA1);                     \
    DST[3][0] = dsr<(BUF)*32768 + (MH)*8192 + 6144>(aA0);                     \
    DST[3][1] = dsr<(BUF)*32768 + (MH)*8192 + 6144>(aA1);                     \
  } while (0)

#define RDB01(BUF) do {                                                       \
    b[0][0] = dsr<(BUF)*32768 + 0   >(aB0);                                   \
    b[0][1] = dsr<(BUF)*32768 + 0   >(aB1);                                   \
    b[1][0] = dsr<(BUF)*32768 + 2048>(aB0);                                   \
    b[1][1] = dsr<(BUF)*32768 + 2048>(aB1);                                   \
  } while (0)

#define RDB23(BUF) do {                                                       \
    b[2][0] = dsr<(BUF)*32768 + 4096>(aB0);                                   \
    b[2][1] = dsr<(BUF)*32768 + 4096>(aB1);                                   \
    b[3][0] = dsr<(BUF)*32768 + 6144>(aB0);                                   \
    b[3][1] = dsr<(BUF)*32768 + 6144>(aB1);                                   \
  } while (0)

#define MFMAQ(AF, RB, NH) do {                                                \
    _Pragma("unroll") for (int mi_ = 0; mi_ < 4; ++mi_)                       \
    _Pragma("unroll") for (int ni_ = 0; ni_ < 2; ++ni_)                       \
    _Pragma("unroll") for (int kk_ = 0; kk_ < 2; ++kk_)                       \
      acc[(RB) + mi_][(NH)*2 + ni_] =                                         \
          __builtin_amdgcn_mfma_f32_16x16x32_bf16(                            \
              AF[mi_][kk_], b[(NH)*2 + ni_][kk_],                             \
              acc[(RB) + mi_][(NH)*2 + ni_], 0, 0, 0);                        \
  } while (0)

#define PRIO1 __builtin_amdgcn_s_setprio(1)
#define PRIO0 __builtin_amdgcn_s_setprio(0)

__global__ __launch_bounds__(512, 2) void gemm_fused(
    const unsigned short* __restrict__ vb, const unsigned short* __restrict__ tb,
    const float* __restrict__ nmask, float* __restrict__ partial) {
  __shared__ unsigned short As[2][256 * 64];   // 64 KB
  __shared__ unsigned short Bs[2][256 * 64];   // 64 KB
  __shared__ float part[256][4];               // 4 KB

  // XCD-aware bijective swizzle: nwg = 1024, 1024 % 8 == 0.
  int lin = blockIdx.y * 32 + blockIdx.x;
  lin = (lin & 7) * 128 + (lin >> 3);
  const int bx = lin & 31, by = lin >> 5;
  const int i0 = by * 256, j0 = bx * 256;

  const int t = threadIdx.x;
  const int w = t >> 6, l = t & 63;
  const int quad = l >> 4, l15 = l & 15;
  const int wm = w >> 2, wn = w & 3;           // 2M x 4N waves

  // Staging lane geometry (pre-swizzled global source, linear LDS dest).
  const int lrow = l >> 3;
  const int lch = (l & 7) ^ lrow;
  const unsigned short* Ag = vb + (size_t)(i0 + w * 8 + lrow) * ND + lch * 8;
  const unsigned short* Bg = tb + (size_t)(j0 + w * 8 + lrow) * ND + lch * 8;
  char* AL0 = (char*)&As[0][0] + w * 1024;
  char* AL1 = (char*)&As[1][0] + w * 1024;
  char* BL0 = (char*)&Bs[0][0] + w * 1024;
  char* BL1 = (char*)&Bs[1][0] + w * 1024;

  // ds_read lane geometry: per-lane byte addresses; subtile walk via
  // offset: immediates; kk=1 chunk via addr^64 (c1 = c0^4).
  const int rA = wm * 128 + l15;               // + MH*64 + mi*16 via imm
  const int rB = wn * 64 + l15;                // + ni*16 via imm
  const int c0 = quad ^ (l & 7);
  const unsigned aA0 = ldsaddr(&As[0][0]) + rA * 128 + c0 * 16;
  const unsigned aA1 = aA0 ^ 64;
  const unsigned aB0 = ldsaddr(&Bs[0][0]) + rB * 128 + c0 * 16;
  const unsigned aB1 = aB0 ^ 64;

  // Prologue: K0 fully -> buf0 (8 loads), K1 A-halves -> buf1 (4 loads).
  STG(Ag, AL0, 0, 0); STG(Ag, AL0, 0, 1);
  STG(Bg, BL0, 0, 0); STG(Bg, BL0, 0, 1);
  STG(Ag, AL1, 1, 0); STG(Ag, AL1, 1, 1);
  VMCNT(4);           // K0 landed; K1-A (4 loads) still in flight
  AS_BARRIER;

  bf16x8 a[4][2], a2[4][2], b[4][2];
  f32x4 acc[8][4] = {};

  // Prime R1(buf0): a + b (16 reads); waited at first P1 lgkm0.
  RDA(0, 0, a); RDB01(0); RDB23(0);
  SCHED_FENCE;

  #pragma unroll 1
  for (int tt = 0; tt < 8; ++tt) {
    const int k0 = 2 * tt, k1 = 2 * tt + 1;
    const bool pf = (tt < 7);
    // ---- P1: wait R1(buf0); issue R2(buf0 a2) under MFMA
    STG(Bg, BL1, k1, 0);
    AS_BARRIER; LGKM0;
    RDA(0, 1, a2);
    SCHED_FENCE;
    PRIO1; MFMAQ(a, 0, 0); PRIO0;
    AS_BARRIER;
    // ---- P2: safety-complete R2 before buf0 restage at P3 (aged ~1 phase)
    STG(Bg, BL1, k1, 1);
    AS_BARRIER; LGKM0;
    PRIO1; MFMAQ(a, 0, 1); PRIO0;
    AS_BARRIER;
    // ---- P3: no wait (a2 completed at P2)
    if (pf) STG(Ag, AL0, k0 + 2, 0);
    AS_BARRIER;
    PRIO1; MFMAQ(a2, 4, 0); PRIO0;
    AS_BARRIER;
    // ---- P4: counted wait -> buf1 landed; issue R1(buf1) under MFMA.
    //          WAR: a,b[0..1] dead -> pre; b[2..3] live in MFMA -> post.
    if (pf) { STG(Ag, AL0, k0 + 2, 1); VMCNT(4); } else { VMCNT(0); }
    AS_BARRIER;
    RDA(1, 0, a); RDB01(1);
    SCHED_FENCE;
    PRIO1; MFMAQ(a2, 4, 1); PRIO0;
    SCHED_FENCE;
    RDB23(1);
    AS_BARRIER;
    // ---- P5: wait R1(buf1); issue R2(buf1 a2) under MFMA
    if (pf) STG(Bg, BL0, k0 + 2, 0);
    AS_BARRIER; LGKM0;
    RDA(1, 1, a2);
    SCHED_FENCE;
    PRIO1; MFMAQ(a, 0, 0); PRIO0;
    AS_BARRIER;
    // ---- P6: safety-complete R2 before buf1 restage at P7
    if (pf) STG(Bg, BL0, k0 + 2, 1);
    AS_BARRIER; LGKM0;
    PRIO1; MFMAQ(a, 0, 1); PRIO0;
    AS_BARRIER;
    // ---- P7: no wait
    if (pf) STG(Ag, AL1, k1 + 2, 0);
    AS_BARRIER;
    PRIO1; MFMAQ(a2, 4, 0); PRIO0;
    AS_BARRIER;
    // ---- P8: counted wait -> buf0(K k0+2) landed; issue R1(buf0) under MFMA
    if (pf) { STG(Ag, AL1, k1 + 2, 1); VMCNT(4); }
    AS_BARRIER;
    if (pf) { RDA(0, 0, a); RDB01(0); }
    SCHED_FENCE;
    PRIO1; MFMAQ(a2, 4, 1); PRIO0;
    SCHED_FENCE;
    if (pf) RDB23(0);
    AS_BARRIER;
  }

  // Epilogue: val = exp(sim/T)*max(n_row,n_col); row-sum over this block's
  // 256 cols. C/D layout (m89): col = l&15 (from B), row = quad*4 + reg.
  const float SCALE = 20.60992915555662f;  // log2(e)/0.07
  float ncol[4];
  #pragma unroll
  for (int ni = 0; ni < 4; ++ni) ncol[ni] = nmask[j0 + wn * 64 + ni * 16 + l15];

  #pragma unroll
  for (int mi = 0; mi < 8; ++mi) {
    float nrow[4], ra[4] = {0.f, 0.f, 0.f, 0.f};
    #pragma unroll
    for (int r = 0; r < 4; ++r)
      nrow[r] = nmask[i0 + wm * 128 + mi * 16 + quad * 4 + r];
    #pragma unroll
    for (int ni = 0; ni < 4; ++ni)
      #pragma unroll
      for (int r = 0; r < 4; ++r)
        ra[r] += exp2f(acc[mi][ni][r] * SCALE) * fmaxf(nrow[r], ncol[ni]);
    #pragma unroll
    for (int r = 0; r < 4; ++r) {
      float v = ra[r];
      v += __shfl_xor(v, 1); v += __shfl_xor(v, 2);
      v += __shfl_xor(v, 4); v += __shfl_xor(v, 8);
      if (l15 == 0) part[wm * 128 + mi * 16 + quad * 4 + r][wn] = v;
    }
  }
  __syncthreads();
  if (t < 256)
    partial[(size_t)bx * NB + i0 + t] =
        part[t][0] + part[t][1] + part[t][2] + part[t][3];
}

// ---------------------------------------------------------------------------
// loss = mean_i log(sum_c partial[c][i] + 1e-8). 32 blocks x 256 threads.
__global__ void finalize(const float* __restrict__ partial, float* __restrict__ out) {
  int r = blockIdx.x * 256 + threadIdx.x;
  float s = 0.f;
  #pragma unroll 4
  for (int c = 0; c < 32; ++c) s += partial[(size_t)c * NB + r];
  float lg = logf(s + 1e-8f);
  #pragma unroll
  for (int m = 32; m; m >>= 1) lg += __shfl_xor(lg, m);
  __shared__ float sred[4];
  if ((threadIdx.x & 63) == 0) sred[threadIdx.x >> 6] = lg;
  __syncthreads();
  if (threadIdx.x == 0)
    atomicAdd(out, (sred[0] + sred[1] + sred[2] + sred[3]) * (1.0f / NB));
}

// ---------------------------------------------------------------------------
extern "C" void kernel_launch(void* const* d_in, const int* in_sizes, int n_in,
                              void* d_out, int out_size, void* d_ws, size_t ws_size,
                              hipStream_t stream) {
  const float* vis = (const float*)d_in[0];
  const float* txt = (const float*)d_in[1];
  // d_in[2] transport_matrix: unused. d_in[3] clean mask: unused.
  const unsigned char* noisy = (const unsigned char*)d_in[4];
  float* out = (float*)d_out;

  char* ws = (char*)d_ws;
  unsigned short* vb = (unsigned short*)ws;                           // 16 MB bf16
  unsigned short* tb = (unsigned short*)(ws + ((size_t)16 << 20));    // 16 MB bf16
  float* nmask = (float*)(ws + ((size_t)32 << 20));                   // 32 KB
  float* partial = (float*)(ws + ((size_t)32 << 20) + (64 << 10));    // 1 MB

  hipMemsetAsync(d_out, 0, sizeof(float), stream);
  prep_mask<<<1, 256, 0, stream>>>(noisy, nmask);
  norm_cast<<<dim3(NB, 2), 256, 0, stream>>>(vis, txt, vb, tb);
  gemm_fused<<<dim3(NB / 256, NB / 256), 512, 0, stream>>>(vb, tb, nmask, partial);
  finalize<<<NB / 256, 256, 0, stream>>>(partial, out);
}